// Round 1
// baseline (333.364 us; speedup 1.0000x reference)
//
#include <hip/hip_runtime.h>

#define B_ 2
#define S_ 2048
#define D_ 1024
#define H_ 16
#define HD_ 64
#define M_ (B_*S_)

typedef __attribute__((ext_vector_type(8))) short bf16x8;
typedef __attribute__((ext_vector_type(4))) float f32x4;
typedef __attribute__((ext_vector_type(4))) unsigned int u32x4;

static __device__ __forceinline__ unsigned short f2bf(float f) {
  unsigned int u = __builtin_bit_cast(unsigned int, f);
  u += 0x7FFFu + ((u >> 16) & 1u);   // RNE
  return (unsigned short)(u >> 16);
}

// ---------- K0: transpose + convert weights: Wt[z][n][k] = bf16(W_z[k][n]) ----------
__global__ void wtrans_kernel(const float* __restrict__ Wq, const float* __restrict__ Wk,
                              const float* __restrict__ Wv, const float* __restrict__ Wo,
                              unsigned short* __restrict__ wt) {
  __shared__ float tile[32][33];
  const float* W = blockIdx.z==0 ? Wq : blockIdx.z==1 ? Wk : blockIdx.z==2 ? Wv : Wo;
  unsigned short* out = wt + (size_t)blockIdx.z * D_ * D_;
  int n0 = blockIdx.x*32, k0 = blockIdx.y*32;
  int tx = threadIdx.x, ty = threadIdx.y;   // 32 x 8
  #pragma unroll
  for (int i=0;i<4;i++) tile[ty+i*8][tx] = W[(size_t)(k0+ty+i*8)*D_ + n0+tx];
  __syncthreads();
  #pragma unroll
  for (int i=0;i<4;i++) out[(size_t)(n0+ty+i*8)*D_ + (k0+tx)] = f2bf(tile[tx][ty+i*8]);
}

// ---------- K1: QKV projection GEMM (x fp32 -> bf16 on the fly) ----------
// C[m][n] = sum_k x[m][k] * Wt_z[n][k];  z=0 -> Q[B,H,S,HD], z=1 -> K[B,H,S,HD], z=2 -> Vt[B,H,HD,S]
__global__ __launch_bounds__(256,2) void gemm_qkv_kernel(
    const float* __restrict__ x, const unsigned short* __restrict__ wt,
    unsigned short* __restrict__ Qo, unsigned short* __restrict__ Ko,
    unsigned short* __restrict__ Vto) {
  __shared__ __align__(16) unsigned short As[128*40];
  __shared__ __align__(16) unsigned short Bs[128*40];
  const int z = blockIdx.z;
  const unsigned short* Wt = wt + (size_t)z * D_ * D_;
  const int m0 = blockIdx.y*128, n0 = blockIdx.x*128;
  const int t = threadIdx.x, lane = t & 63, wid = t >> 6;
  const int srow = t >> 1, sseg = t & 1;
  const int wr = (wid>>1)*64, wc = (wid&1)*64;
  const int l15 = lane & 15, lg = lane >> 4;

  f32x4 acc[4][4];
  #pragma unroll
  for (int m=0;m<4;m++)
    #pragma unroll
    for (int n=0;n<4;n++) acc[m][n] = f32x4{0.f,0.f,0.f,0.f};

  for (int k0=0;k0<D_;k0+=32) {
    __syncthreads();
    { // A stage: fp32 -> bf16
      const float* src = x + (size_t)(m0+srow)*D_ + k0 + sseg*16;
      float4 f0 = ((const float4*)src)[0];
      float4 f1 = ((const float4*)src)[1];
      float4 f2 = ((const float4*)src)[2];
      float4 f3 = ((const float4*)src)[3];
      bf16x8 w0, w1;
      w0[0]=(short)f2bf(f0.x); w0[1]=(short)f2bf(f0.y); w0[2]=(short)f2bf(f0.z); w0[3]=(short)f2bf(f0.w);
      w0[4]=(short)f2bf(f1.x); w0[5]=(short)f2bf(f1.y); w0[6]=(short)f2bf(f1.z); w0[7]=(short)f2bf(f1.w);
      w1[0]=(short)f2bf(f2.x); w1[1]=(short)f2bf(f2.y); w1[2]=(short)f2bf(f2.z); w1[3]=(short)f2bf(f2.w);
      w1[4]=(short)f2bf(f3.x); w1[5]=(short)f2bf(f3.y); w1[6]=(short)f2bf(f3.z); w1[7]=(short)f2bf(f3.w);
      *(bf16x8*)&As[srow*40 + sseg*16]     = w0;
      *(bf16x8*)&As[srow*40 + sseg*16 + 8] = w1;
    }
    { // B stage: bf16 copy
      const u32x4* src = (const u32x4*)(Wt + (size_t)(n0+srow)*D_ + k0 + sseg*16);
      u32x4 v0 = src[0], v1 = src[1];
      *(u32x4*)&Bs[srow*40 + sseg*16]     = v0;
      *(u32x4*)&Bs[srow*40 + sseg*16 + 8] = v1;
    }
    __syncthreads();
    bf16x8 af[4], bfr[4];
    #pragma unroll
    for (int m=0;m<4;m++) af[m]  = *(const bf16x8*)&As[(wr+m*16+l15)*40 + lg*8];
    #pragma unroll
    for (int n=0;n<4;n++) bfr[n] = *(const bf16x8*)&Bs[(wc+n*16+l15)*40 + lg*8];
    #pragma unroll
    for (int m=0;m<4;m++)
      #pragma unroll
      for (int n=0;n<4;n++)
        acc[m][n] = __builtin_amdgcn_mfma_f32_16x16x32_bf16(af[m], bfr[n], acc[m][n], 0,0,0);
  }

  #pragma unroll
  for (int m=0;m<4;m++) {
    #pragma unroll
    for (int n=0;n<4;n++) {
      #pragma unroll
      for (int r=0;r<4;r++) {
        int gm = m0 + wr + m*16 + lg*4 + r;
        int gn = n0 + wc + n*16 + l15;
        int b = gm >> 11, s = gm & (S_-1);
        int h = gn >> 6,  d = gn & 63;
        unsigned short val = f2bf(acc[m][n][r]);
        if (z==0)      Qo[(((size_t)(b*H_+h))*S_ + s)*HD_ + d] = val;
        else if (z==1) Ko[(((size_t)(b*H_+h))*S_ + s)*HD_ + d] = val;
        else           Vto[(((size_t)(b*H_+h))*HD_ + d)*S_ + s] = val;
      }
    }
  }
}

// ---------- K2: causal flash attention, 1 wave per 16-row Q tile ----------
__global__ __launch_bounds__(256,2) void attn_kernel(
    const unsigned short* __restrict__ Q, const unsigned short* __restrict__ K,
    const unsigned short* __restrict__ Vt, unsigned short* __restrict__ ctx) {
  __shared__ __align__(16) unsigned short P_lds[4][16*40];
  const int t = threadIdx.x, lane = t & 63, wid = t >> 6;
  const int tile = blockIdx.x*4 + wid;          // 4096 tiles
  const int bh = tile >> 7;                     // /128 q-tiles per (b,h)
  const int q0 = (tile & 127) * 16;
  const int b = bh >> 4, h = bh & 15;
  const unsigned short* Qp = Q  + (size_t)bh * S_ * HD_;
  const unsigned short* Kp = K  + (size_t)bh * S_ * HD_;
  const unsigned short* Vp = Vt + (size_t)bh * HD_ * S_;
  const int l15 = lane & 15, lg = lane >> 4;
  const int dof = lg * 8;

  bf16x8 qf0 = *(const bf16x8*)(Qp + (size_t)(q0 + l15)*HD_ + dof);
  bf16x8 qf1 = *(const bf16x8*)(Qp + (size_t)(q0 + l15)*HD_ + 32 + dof);

  f32x4 o[4];
  #pragma unroll
  for (int dt=0;dt<4;dt++) o[dt] = f32x4{0.f,0.f,0.f,0.f};
  float mrow[4] = {-INFINITY,-INFINITY,-INFINITY,-INFINITY};
  float lrow[4] = {0.f,0.f,0.f,0.f};
  const float c = 0.18033688011112042f;  // log2(e)/8  (softmax scale 1/sqrt(64))

  const int nchunk = (q0 + 16 + 31) >> 5;
  unsigned short* pl = &P_lds[wid][0];

  for (int ch=0; ch<nchunk; ++ch) {
    const int kk0 = ch*32;
    bf16x8 kf00 = *(const bf16x8*)(Kp + (size_t)(kk0      + l15)*HD_ + dof);
    bf16x8 kf01 = *(const bf16x8*)(Kp + (size_t)(kk0      + l15)*HD_ + 32 + dof);
    bf16x8 kf10 = *(const bf16x8*)(Kp + (size_t)(kk0 + 16 + l15)*HD_ + dof);
    bf16x8 kf11 = *(const bf16x8*)(Kp + (size_t)(kk0 + 16 + l15)*HD_ + 32 + dof);
    f32x4 s0 = f32x4{0.f,0.f,0.f,0.f}, s1 = f32x4{0.f,0.f,0.f,0.f};
    s0 = __builtin_amdgcn_mfma_f32_16x16x32_bf16(qf0, kf00, s0, 0,0,0);
    s0 = __builtin_amdgcn_mfma_f32_16x16x32_bf16(qf1, kf01, s0, 0,0,0);
    s1 = __builtin_amdgcn_mfma_f32_16x16x32_bf16(qf0, kf10, s1, 0,0,0);
    s1 = __builtin_amdgcn_mfma_f32_16x16x32_bf16(qf1, kf11, s1, 0,0,0);

    if (ch == nchunk-1) {   // causal mask (only last chunk can cross the diagonal)
      #pragma unroll
      for (int r=0;r<4;r++) {
        int qg = q0 + lg*4 + r;
        if (kk0 + l15 > qg)      s0[r] = -INFINITY;
        if (kk0 + 16 + l15 > qg) s1[r] = -INFINITY;
      }
    }

    float mx[4];
    #pragma unroll
    for (int r=0;r<4;r++) mx[r] = fmaxf(s0[r], s1[r]);
    #pragma unroll
    for (int off=1; off<16; off<<=1)
      #pragma unroll
      for (int r=0;r<4;r++) mx[r] = fmaxf(mx[r], __shfl_xor(mx[r], off));

    float corr[4], p0[4], p1[4], rs[4];
    #pragma unroll
    for (int r=0;r<4;r++) {
      float mn = fmaxf(mrow[r], mx[r]);
      corr[r] = exp2f((mrow[r]-mn)*c);
      mrow[r] = mn;
      p0[r] = exp2f((s0[r]-mn)*c);
      p1[r] = exp2f((s1[r]-mn)*c);
      rs[r] = p0[r] + p1[r];
    }
    #pragma unroll
    for (int off=1; off<16; off<<=1)
      #pragma unroll
      for (int r=0;r<4;r++) rs[r] += __shfl_xor(rs[r], off);
    #pragma unroll
    for (int r=0;r<4;r++) lrow[r] = lrow[r]*corr[r] + rs[r];
    #pragma unroll
    for (int dt=0;dt<4;dt++)
      #pragma unroll
      for (int r=0;r<4;r++) o[dt][r] *= corr[r];

    // P (C-layout) -> LDS -> A-layout fragment
    #pragma unroll
    for (int r=0;r<4;r++) {
      int prow = lg*4 + r;
      pl[prow*40 + l15]      = f2bf(p0[r]);
      pl[prow*40 + 16 + l15] = f2bf(p1[r]);
    }
    asm volatile("s_waitcnt lgkmcnt(0)" ::: "memory");
    bf16x8 pf = *(const bf16x8*)&pl[l15*40 + lg*8];

    #pragma unroll
    for (int dt=0; dt<4; dt++) {
      bf16x8 vf = *(const bf16x8*)(Vp + (size_t)(dt*16 + l15)*S_ + kk0 + lg*8);
      o[dt] = __builtin_amdgcn_mfma_f32_16x16x32_bf16(pf, vf, o[dt], 0,0,0);
    }
  }

  float inv[4];
  #pragma unroll
  for (int r=0;r<4;r++) inv[r] = 1.0f / lrow[r];
  #pragma unroll
  for (int dt=0;dt<4;dt++)
    #pragma unroll
    for (int r=0;r<4;r++) {
      size_t row = (size_t)(b*S_ + q0 + lg*4 + r);
      ctx[row*D_ + h*HD_ + dt*16 + l15] = f2bf(o[dt][r]*inv[r]);
    }
}

// ---------- K3: output projection GEMM + bias (bf16 A, fp32 out) ----------
__global__ __launch_bounds__(256,2) void gemm_out_kernel(
    const unsigned short* __restrict__ ctx, const unsigned short* __restrict__ WtO,
    const float* __restrict__ bo, float* __restrict__ out) {
  __shared__ __align__(16) unsigned short As[128*40];
  __shared__ __align__(16) unsigned short Bs[128*40];
  const int m0 = blockIdx.y*128, n0 = blockIdx.x*128;
  const int t = threadIdx.x, lane = t & 63, wid = t >> 6;
  const int srow = t >> 1, sseg = t & 1;
  const int wr = (wid>>1)*64, wc = (wid&1)*64;
  const int l15 = lane & 15, lg = lane >> 4;

  f32x4 acc[4][4];
  #pragma unroll
  for (int m=0;m<4;m++)
    #pragma unroll
    for (int n=0;n<4;n++) acc[m][n] = f32x4{0.f,0.f,0.f,0.f};

  for (int k0=0;k0<D_;k0+=32) {
    __syncthreads();
    {
      const u32x4* src = (const u32x4*)(ctx + (size_t)(m0+srow)*D_ + k0 + sseg*16);
      u32x4 v0 = src[0], v1 = src[1];
      *(u32x4*)&As[srow*40 + sseg*16]     = v0;
      *(u32x4*)&As[srow*40 + sseg*16 + 8] = v1;
    }
    {
      const u32x4* src = (const u32x4*)(WtO + (size_t)(n0+srow)*D_ + k0 + sseg*16);
      u32x4 v0 = src[0], v1 = src[1];
      *(u32x4*)&Bs[srow*40 + sseg*16]     = v0;
      *(u32x4*)&Bs[srow*40 + sseg*16 + 8] = v1;
    }
    __syncthreads();
    bf16x8 af[4], bfr[4];
    #pragma unroll
    for (int m=0;m<4;m++) af[m]  = *(const bf16x8*)&As[(wr+m*16+l15)*40 + lg*8];
    #pragma unroll
    for (int n=0;n<4;n++) bfr[n] = *(const bf16x8*)&Bs[(wc+n*16+l15)*40 + lg*8];
    #pragma unroll
    for (int m=0;m<4;m++)
      #pragma unroll
      for (int n=0;n<4;n++)
        acc[m][n] = __builtin_amdgcn_mfma_f32_16x16x32_bf16(af[m], bfr[n], acc[m][n], 0,0,0);
  }

  #pragma unroll
  for (int n=0;n<4;n++) {
    float bias = bo[n0 + wc + n*16 + l15];
    #pragma unroll
    for (int m=0;m<4;m++)
      #pragma unroll
      for (int r=0;r<4;r++) {
        int gm = m0 + wr + m*16 + lg*4 + r;
        int gn = n0 + wc + n*16 + l15;
        out[(size_t)gm*D_ + gn] = acc[m][n][r] + bias;
      }
  }
}

extern "C" void kernel_launch(void* const* d_in, const int* in_sizes, int n_in,
                              void* d_out, int out_size, void* d_ws, size_t ws_size,
                              hipStream_t stream) {
  (void)in_sizes; (void)n_in; (void)out_size; (void)ws_size;
  const float* x  = (const float*)d_in[0];
  const float* Wq = (const float*)d_in[1];
  const float* Wk = (const float*)d_in[2];
  const float* Wv = (const float*)d_in[3];
  const float* Wo = (const float*)d_in[4];
  const float* bo = (const float*)d_in[5];
  float* out = (float*)d_out;

  unsigned short* wt  = (unsigned short*)d_ws;            // 4 * D*D bf16 (transposed weights)
  unsigned short* Qb  = wt  + (size_t)4*D_*D_;            // [B,H,S,HD]
  unsigned short* Kb  = Qb  + (size_t)M_*D_;              // [B,H,S,HD]
  unsigned short* Vtb = Kb  + (size_t)M_*D_;              // [B,H,HD,S]
  unsigned short* ctb = Vtb + (size_t)M_*D_;              // [B,S,D]

  wtrans_kernel<<<dim3(32,32,4), dim3(32,8), 0, stream>>>(Wq, Wk, Wv, Wo, wt);
  gemm_qkv_kernel<<<dim3(8,32,3), 256, 0, stream>>>(x, wt, Qb, Kb, Vtb);
  attn_kernel<<<dim3(1024), 256, 0, stream>>>(Qb, Kb, Vtb, ctb);
  gemm_out_kernel<<<dim3(8,32), 256, 0, stream>>>(ctb, wt + (size_t)3*D_*D_, bo, out);
}

// Round 3
// 152.569 us; speedup vs baseline: 2.1850x; 2.1850x over previous
//
#include <hip/hip_runtime.h>

#define B_ 2
#define S_ 2048
#define D_ 1024
#define H_ 16
#define HD_ 64
#define M_ (B_*S_)

typedef __attribute__((ext_vector_type(8))) short bf16x8;
typedef __attribute__((ext_vector_type(4))) short s16x4;
typedef __attribute__((ext_vector_type(4))) float f32x4;
typedef __attribute__((ext_vector_type(4))) unsigned int u32x4;

static __device__ __forceinline__ unsigned short f2bf(float f) {
  unsigned int u = __builtin_bit_cast(unsigned int, f);
  u += 0x7FFFu + ((u >> 16) & 1u);   // RNE
  return (unsigned short)(u >> 16);
}

static __device__ __forceinline__ void gload_lds16(const void* g, void* l) {
  __builtin_amdgcn_global_load_lds(
      (const __attribute__((address_space(1))) unsigned int*)g,
      (__attribute__((address_space(3))) unsigned int*)l, 16, 0, 0);
}

// ---------- K0: transpose + convert weights: Wt[z][n][k] = bf16(W_z[k][n]) ----------
__global__ void wtrans_kernel(const float* __restrict__ Wq, const float* __restrict__ Wk,
                              const float* __restrict__ Wv, const float* __restrict__ Wo,
                              unsigned short* __restrict__ wt) {
  __shared__ float tile[32][33];
  const float* W = blockIdx.z==0 ? Wq : blockIdx.z==1 ? Wk : blockIdx.z==2 ? Wv : Wo;
  unsigned short* out = wt + (size_t)blockIdx.z * D_ * D_;
  int n0 = blockIdx.x*32, k0 = blockIdx.y*32;
  int tx = threadIdx.x, ty = threadIdx.y;   // 32 x 8
  #pragma unroll
  for (int i=0;i<4;i++) tile[ty+i*8][tx] = W[(size_t)(k0+ty+i*8)*D_ + n0+tx];
  __syncthreads();
  #pragma unroll
  for (int i=0;i<4;i++) out[(size_t)(n0+ty+i*8)*D_ + (k0+tx)] = f2bf(tile[tx][ty+i*8]);
}

// ---------- K1: QKV projection GEMM (x fp32 -> bf16 on the fly) ----------
__global__ __launch_bounds__(256,2) void gemm_qkv_kernel(
    const float* __restrict__ x, const unsigned short* __restrict__ wt,
    unsigned short* __restrict__ Qo, unsigned short* __restrict__ Ko,
    unsigned short* __restrict__ Vto) {
  __shared__ __align__(16) unsigned short As[128*40];
  __shared__ __align__(16) unsigned short Bs[128*40];
  const int z = blockIdx.z;
  const unsigned short* Wt = wt + (size_t)z * D_ * D_;
  const int m0 = blockIdx.y*128, n0 = blockIdx.x*128;
  const int t = threadIdx.x, lane = t & 63, wid = t >> 6;
  const int srow = t >> 1, sseg = t & 1;
  const int wr = (wid>>1)*64, wc = (wid&1)*64;
  const int l15 = lane & 15, lg = lane >> 4;

  f32x4 acc[4][4];
  #pragma unroll
  for (int m=0;m<4;m++)
    #pragma unroll
    for (int n=0;n<4;n++) acc[m][n] = f32x4{0.f,0.f,0.f,0.f};

  for (int k0=0;k0<D_;k0+=32) {
    __syncthreads();
    { // A stage: fp32 -> bf16
      const float* src = x + (size_t)(m0+srow)*D_ + k0 + sseg*16;
      float4 f0 = ((const float4*)src)[0];
      float4 f1 = ((const float4*)src)[1];
      float4 f2 = ((const float4*)src)[2];
      float4 f3 = ((const float4*)src)[3];
      bf16x8 w0, w1;
      w0[0]=(short)f2bf(f0.x); w0[1]=(short)f2bf(f0.y); w0[2]=(short)f2bf(f0.z); w0[3]=(short)f2bf(f0.w);
      w0[4]=(short)f2bf(f1.x); w0[5]=(short)f2bf(f1.y); w0[6]=(short)f2bf(f1.z); w0[7]=(short)f2bf(f1.w);
      w1[0]=(short)f2bf(f2.x); w1[1]=(short)f2bf(f2.y); w1[2]=(short)f2bf(f2.z); w1[3]=(short)f2bf(f2.w);
      w1[4]=(short)f2bf(f3.x); w1[5]=(short)f2bf(f3.y); w1[6]=(short)f2bf(f3.z); w1[7]=(short)f2bf(f3.w);
      *(bf16x8*)&As[srow*40 + sseg*16]     = w0;
      *(bf16x8*)&As[srow*40 + sseg*16 + 8] = w1;
    }
    { // B stage: bf16 copy
      const u32x4* src = (const u32x4*)(Wt + (size_t)(n0+srow)*D_ + k0 + sseg*16);
      u32x4 v0 = src[0], v1 = src[1];
      *(u32x4*)&Bs[srow*40 + sseg*16]     = v0;
      *(u32x4*)&Bs[srow*40 + sseg*16 + 8] = v1;
    }
    __syncthreads();
    bf16x8 af[4], bfr[4];
    #pragma unroll
    for (int m=0;m<4;m++) af[m]  = *(const bf16x8*)&As[(wr+m*16+l15)*40 + lg*8];
    #pragma unroll
    for (int n=0;n<4;n++) bfr[n] = *(const bf16x8*)&Bs[(wc+n*16+l15)*40 + lg*8];
    #pragma unroll
    for (int m=0;m<4;m++)
      #pragma unroll
      for (int n=0;n<4;n++)
        acc[m][n] = __builtin_amdgcn_mfma_f32_16x16x32_bf16(af[m], bfr[n], acc[m][n], 0,0,0);
  }

  #pragma unroll
  for (int m=0;m<4;m++) {
    #pragma unroll
    for (int n=0;n<4;n++) {
      #pragma unroll
      for (int r=0;r<4;r++) {
        int gm = m0 + wr + m*16 + lg*4 + r;
        int gn = n0 + wc + n*16 + l15;
        int b = gm >> 11, s = gm & (S_-1);
        int h = gn >> 6,  d = gn & 63;
        unsigned short val = f2bf(acc[m][n][r]);
        if (z==0)      Qo[(((size_t)(b*H_+h))*S_ + s)*HD_ + d] = val;
        else if (z==1) Ko[(((size_t)(b*H_+h))*S_ + s)*HD_ + d] = val;
        else           Vto[(((size_t)(b*H_+h))*HD_ + d)*S_ + s] = val;
      }
    }
  }
}

// ---------- K2: causal flash attention v2 ----------
// Block = 64 q-rows (4 waves x 16), KVBLK=64 staged in LDS (double-buffered,
// XOR-swizzled via pre-swizzled global source). Swapped QK^T -> lane-local rows.
__global__ __launch_bounds__(256,2) void attn_kernel(
    const unsigned short* __restrict__ Q, const unsigned short* __restrict__ K,
    const unsigned short* __restrict__ Vt, unsigned short* __restrict__ ctx) {
  __shared__ __align__(16) unsigned short KT[2][64*64];
  __shared__ __align__(16) unsigned short VT[2][64*64];
  __shared__ __align__(16) unsigned short PL[4][16*72];
  const int t = threadIdx.x, lane = t & 63, wid = t >> 6;
  const int bh = blockIdx.x & 31;
  const int qt = 31 - (int)(blockIdx.x >> 5);   // heavy tiles first
  const int b = bh >> 4, h = bh & 15;
  const int q0 = qt * 64, qw0 = q0 + wid * 16;
  const int nchunk = qt + 1;
  const unsigned short* Qp = Q  + (size_t)bh * S_ * HD_;
  const unsigned short* Kp = K  + (size_t)bh * S_ * HD_;
  const unsigned short* Vp = Vt + (size_t)bh * HD_ * S_;
  const int l15 = lane & 15, lg = lane >> 4;
  const int rsub = lane >> 3, slot = lane & 7;
  const int sslot = slot ^ rsub;                // source pre-swizzle (row&7 == rsub)

  // Q fragments (B-operand of swapped QK^T): Q[qw0+l15][d contiguous]
  bf16x8 qf0 = *(const bf16x8*)(Qp + (size_t)(qw0 + l15)*HD_ + lg*8);
  bf16x8 qf1 = *(const bf16x8*)(Qp + (size_t)(qw0 + l15)*HD_ + 32 + lg*8);

  f32x4 o[4];
  #pragma unroll
  for (int dt=0;dt<4;dt++) o[dt] = f32x4{0.f,0.f,0.f,0.f};
  float m = -INFINITY, lsum = 0.f;
  const float c = 0.18033688011112042f;  // log2(e)/8

  // stage chunk ch into buffer buf: wave stages K rows 16w..16w+15, V rows 16w..16w+15
  auto stage = [&](int ch, int buf) {
    const int kk0 = ch * 64;
    #pragma unroll
    for (int j=0;j<2;j++) {
      int row = 16*wid + 8*j + rsub;
      gload_lds16(Kp + (size_t)(kk0 + row)*HD_ + sslot*8, &KT[buf][(16*wid + 8*j)*64]);
      gload_lds16(Vp + (size_t)row*S_ + kk0 + sslot*8,    &VT[buf][(16*wid + 8*j)*64]);
    }
  };

  stage(0, 0);
  __syncthreads();

  for (int ch=0; ch<nchunk; ++ch) {
    const int cur = ch & 1;
    const int kk0 = ch * 64;
    if (ch + 1 < nchunk) stage(ch+1, cur^1);

    const unsigned short* Kt = &KT[cur][0];
    const unsigned short* Vv = &VT[cur][0];

    // QK^T swapped: st[kt] holds S^T: k = kk0+kt*16+lg*4+r, q = qw0+l15
    f32x4 st[4];
    #pragma unroll
    for (int kt=0; kt<4; ++kt) {
      int row = kt*16 + l15;
      int sw = (row & 7) << 4;
      bf16x8 kf0 = *(const bf16x8*)((const char*)Kt + row*128 + ((lg*16)      ^ sw));
      bf16x8 kf1 = *(const bf16x8*)((const char*)Kt + row*128 + ((64 + lg*16) ^ sw));
      f32x4 z = f32x4{0.f,0.f,0.f,0.f};
      z = __builtin_amdgcn_mfma_f32_16x16x32_bf16(kf0, qf0, z, 0,0,0);
      z = __builtin_amdgcn_mfma_f32_16x16x32_bf16(kf1, qf1, z, 0,0,0);
      st[kt] = z;
    }

    if (ch == nchunk-1) {  // causal mask (only last chunk crosses the diagonal)
      const int q = qw0 + l15;
      #pragma unroll
      for (int kt=0;kt<4;kt++)
        #pragma unroll
        for (int r=0;r<4;r++)
          if (kk0 + kt*16 + lg*4 + r > q) st[kt][r] = -INFINITY;
    }

    // online softmax: lane-local row (q = qw0+l15)
    float mx = st[0][0];
    #pragma unroll
    for (int kt=0;kt<4;kt++)
      #pragma unroll
      for (int r=0;r<4;r++) mx = fmaxf(mx, st[kt][r]);
    mx = fmaxf(mx, __shfl_xor(mx, 16));
    mx = fmaxf(mx, __shfl_xor(mx, 32));
    float mn = fmaxf(m, mx);
    float corr = exp2f((m - mn) * c);
    m = mn;
    float rs = 0.f;
    #pragma unroll
    for (int kt=0;kt<4;kt++)
      #pragma unroll
      for (int r=0;r<4;r++) {
        float p = exp2f((st[kt][r] - mn) * c);
        st[kt][r] = p;
        rs += p;
      }
    rs += __shfl_xor(rs, 16);
    rs += __shfl_xor(rs, 32);
    lsum = lsum * corr + rs;

    // P (lane-local rows) -> LDS (per-wave, packed b64 writes)
    #pragma unroll
    for (int kt=0;kt<4;kt++) {
      s16x4 pk;
      pk[0]=(short)f2bf(st[kt][0]); pk[1]=(short)f2bf(st[kt][1]);
      pk[2]=(short)f2bf(st[kt][2]); pk[3]=(short)f2bf(st[kt][3]);
      *(s16x4*)&PL[wid][l15*72 + kt*16 + lg*4] = pk;
    }

    // rescale O (rows q = qw0+lg*4+r; corr lives in lane l15==row)
    float oc[4];
    #pragma unroll
    for (int r=0;r<4;r++) oc[r] = __shfl(corr, lg*4 + r);
    #pragma unroll
    for (int dt=0;dt<4;dt++)
      #pragma unroll
      for (int r=0;r<4;r++) o[dt][r] *= oc[r];

    bf16x8 pf0 = *(const bf16x8*)&PL[wid][l15*72 + lg*8];
    bf16x8 pf1 = *(const bf16x8*)&PL[wid][l15*72 + 32 + lg*8];

    #pragma unroll
    for (int dt=0;dt<4;dt++) {
      int row = dt*16 + l15;
      int sw = (row & 7) << 4;
      bf16x8 vf0 = *(const bf16x8*)((const char*)Vv + row*128 + ((lg*16)      ^ sw));
      bf16x8 vf1 = *(const bf16x8*)((const char*)Vv + row*128 + ((64 + lg*16) ^ sw));
      o[dt] = __builtin_amdgcn_mfma_f32_16x16x32_bf16(pf0, vf0, o[dt], 0,0,0);
      o[dt] = __builtin_amdgcn_mfma_f32_16x16x32_bf16(pf1, vf1, o[dt], 0,0,0);
    }

    __syncthreads();   // drains vmcnt (next chunk staged) + protects K/V buffers
  }

  float li = 1.f / lsum;
  float lr[4];
  #pragma unroll
  for (int r=0;r<4;r++) lr[r] = __shfl(li, lg*4 + r);
  #pragma unroll
  for (int dt=0;dt<4;dt++)
    #pragma unroll
    for (int r=0;r<4;r++) {
      size_t row = (size_t)(b*S_ + qw0 + lg*4 + r);
      ctx[row*D_ + h*HD_ + dt*16 + l15] = f2bf(o[dt][r] * lr[r]);
    }
}

// ---------- K3: output projection GEMM + bias (bf16 A, fp32 out) ----------
__global__ __launch_bounds__(256,2) void gemm_out_kernel(
    const unsigned short* __restrict__ ctx, const unsigned short* __restrict__ WtO,
    const float* __restrict__ bo, float* __restrict__ out) {
  __shared__ __align__(16) unsigned short As[128*40];
  __shared__ __align__(16) unsigned short Bs[128*40];
  const int m0 = blockIdx.y*128, n0 = blockIdx.x*128;
  const int t = threadIdx.x, lane = t & 63, wid = t >> 6;
  const int srow = t >> 1, sseg = t & 1;
  const int wr = (wid>>1)*64, wc = (wid&1)*64;
  const int l15 = lane & 15, lg = lane >> 4;

  f32x4 acc[4][4];
  #pragma unroll
  for (int m=0;m<4;m++)
    #pragma unroll
    for (int n=0;n<4;n++) acc[m][n] = f32x4{0.f,0.f,0.f,0.f};

  for (int k0=0;k0<D_;k0+=32) {
    __syncthreads();
    {
      const u32x4* src = (const u32x4*)(ctx + (size_t)(m0+srow)*D_ + k0 + sseg*16);
      u32x4 v0 = src[0], v1 = src[1];
      *(u32x4*)&As[srow*40 + sseg*16]     = v0;
      *(u32x4*)&As[srow*40 + sseg*16 + 8] = v1;
    }
    {
      const u32x4* src = (const u32x4*)(WtO + (size_t)(n0+srow)*D_ + k0 + sseg*16);
      u32x4 v0 = src[0], v1 = src[1];
      *(u32x4*)&Bs[srow*40 + sseg*16]     = v0;
      *(u32x4*)&Bs[srow*40 + sseg*16 + 8] = v1;
    }
    __syncthreads();
    bf16x8 af[4], bfr[4];
    #pragma unroll
    for (int m=0;m<4;m++) af[m]  = *(const bf16x8*)&As[(wr+m*16+l15)*40 + lg*8];
    #pragma unroll
    for (int n=0;n<4;n++) bfr[n] = *(const bf16x8*)&Bs[(wc+n*16+l15)*40 + lg*8];
    #pragma unroll
    for (int m=0;m<4;m++)
      #pragma unroll
      for (int n=0;n<4;n++)
        acc[m][n] = __builtin_amdgcn_mfma_f32_16x16x32_bf16(af[m], bfr[n], acc[m][n], 0,0,0);
  }

  #pragma unroll
  for (int n=0;n<4;n++) {
    float bias = bo[n0 + wc + n*16 + l15];
    #pragma unroll
    for (int m=0;m<4;m++)
      #pragma unroll
      for (int r=0;r<4;r++) {
        int gm = m0 + wr + m*16 + lg*4 + r;
        int gn = n0 + wc + n*16 + l15;
        out[(size_t)gm*D_ + gn] = acc[m][n][r] + bias;
      }
  }
}

extern "C" void kernel_launch(void* const* d_in, const int* in_sizes, int n_in,
                              void* d_out, int out_size, void* d_ws, size_t ws_size,
                              hipStream_t stream) {
  (void)in_sizes; (void)n_in; (void)out_size; (void)ws_size;
  const float* x  = (const float*)d_in[0];
  const float* Wq = (const float*)d_in[1];
  const float* Wk = (const float*)d_in[2];
  const float* Wv = (const float*)d_in[3];
  const float* Wo = (const float*)d_in[4];
  const float* bo = (const float*)d_in[5];
  float* out = (float*)d_out;

  unsigned short* wt  = (unsigned short*)d_ws;            // 4 * D*D bf16 (transposed weights)
  unsigned short* Qb  = wt  + (size_t)4*D_*D_;            // [B,H,S,HD]
  unsigned short* Kb  = Qb  + (size_t)M_*D_;              // [B,H,S,HD]
  unsigned short* Vtb = Kb  + (size_t)M_*D_;              // [B,H,HD,S]
  unsigned short* ctb = Vtb + (size_t)M_*D_;              // [B,S,D]

  wtrans_kernel<<<dim3(32,32,4), dim3(32,8), 0, stream>>>(Wq, Wk, Wv, Wo, wt);
  gemm_qkv_kernel<<<dim3(8,32,3), 256, 0, stream>>>(x, wt, Qb, Kb, Vtb);
  attn_kernel<<<dim3(1024), 256, 0, stream>>>(Qb, Kb, Vtb, ctb);
  gemm_out_kernel<<<dim3(8,32), 256, 0, stream>>>(ctb, wt + (size_t)3*D_*D_, bo, out);
}

// Round 4
// 121.543 us; speedup vs baseline: 2.7428x; 1.2553x over previous
//
#include <hip/hip_runtime.h>

#define B_ 2
#define S_ 2048
#define D_ 1024
#define H_ 16
#define HD_ 64
#define M_ (B_*S_)

typedef __attribute__((ext_vector_type(8))) short bf16x8;
typedef __attribute__((ext_vector_type(4))) short s16x4;
typedef __attribute__((ext_vector_type(4))) float f32x4;
typedef __attribute__((ext_vector_type(4))) unsigned int u32x4;

static __device__ __forceinline__ unsigned short f2bf(float f) {
  unsigned int u = __builtin_bit_cast(unsigned int, f);
  u += 0x7FFFu + ((u >> 16) & 1u);   // RNE
  return (unsigned short)(u >> 16);
}

static __device__ __forceinline__ void gload_lds16(const void* g, void* l) {
  __builtin_amdgcn_global_load_lds(
      (const __attribute__((address_space(1))) unsigned int*)g,
      (__attribute__((address_space(3))) unsigned int*)l, 16, 0, 0);
}

// ---------- K0a: x fp32 -> bf16 ----------
__global__ __launch_bounds__(256) void xcvt_kernel(const float* __restrict__ x,
                                                   unsigned short* __restrict__ xb) {
  size_t i = ((size_t)blockIdx.x * 256 + threadIdx.x) * 8;
  float4 a = ((const float4*)(x + i))[0];
  float4 b = ((const float4*)(x + i))[1];
  bf16x8 w;
  w[0]=(short)f2bf(a.x); w[1]=(short)f2bf(a.y); w[2]=(short)f2bf(a.z); w[3]=(short)f2bf(a.w);
  w[4]=(short)f2bf(b.x); w[5]=(short)f2bf(b.y); w[6]=(short)f2bf(b.z); w[7]=(short)f2bf(b.w);
  *(bf16x8*)(xb + i) = w;
}

// ---------- K0b: transpose + convert weights: Wt[z][n][k] = bf16(W_z[k][n]) ----------
__global__ void wtrans_kernel(const float* __restrict__ Wq, const float* __restrict__ Wk,
                              const float* __restrict__ Wv, const float* __restrict__ Wo,
                              unsigned short* __restrict__ wt) {
  __shared__ float tile[32][33];
  const float* W = blockIdx.z==0 ? Wq : blockIdx.z==1 ? Wk : blockIdx.z==2 ? Wv : Wo;
  unsigned short* out = wt + (size_t)blockIdx.z * D_ * D_;
  int n0 = blockIdx.x*32, k0 = blockIdx.y*32;
  int tx = threadIdx.x, ty = threadIdx.y;   // 32 x 8
  #pragma unroll
  for (int i=0;i<4;i++) tile[ty+i*8][tx] = W[(size_t)(k0+ty+i*8)*D_ + n0+tx];
  __syncthreads();
  #pragma unroll
  for (int i=0;i<4;i++) out[(size_t)(n0+ty+i*8)*D_ + (k0+tx)] = f2bf(tile[tx][ty+i*8]);
}

// ---------- shared GEMM tile body (m97 structure, BK=64, XOR-swizzled LDS) ----------
// A: bf16 [*][1024] row-major (contiguous k); B: bf16 Wt[n][k].
// acc[m][n]: C[m0+wr+m*16+lg*4+r][n0+wc+n*16+l15]

#define GEMM_K_LOOP(Abase, Bbase)                                                     \
  for (int ks = 0; ks < 16; ++ks) {                                                   \
    const int k0 = ks * 64;                                                           \
    __syncthreads();                                                                  \
    _Pragma("unroll")                                                                 \
    for (int p = 0; p < 4; ++p) {                                                     \
      int c = p*256 + t;                                                              \
      int row = c >> 3, sl = (c & 7) ^ (row & 7);                                     \
      gload_lds16(Abase + (size_t)row*D_ + k0 + sl*8, &As[(p*256 + wid*64)*8]);       \
    }                                                                                 \
    _Pragma("unroll")                                                                 \
    for (int p = 0; p < 4; ++p) {                                                     \
      int c = p*256 + t;                                                              \
      int row = c >> 3, sl = (c & 7) ^ (row & 7);                                     \
      gload_lds16(Bbase + (size_t)row*D_ + k0 + sl*8, &Bs[(p*256 + wid*64)*8]);       \
    }                                                                                 \
    __syncthreads();                                                                  \
    _Pragma("unroll")                                                                 \
    for (int kk = 0; kk < 2; ++kk) {                                                  \
      bf16x8 af[4], bfr[4];                                                           \
      _Pragma("unroll")                                                               \
      for (int m = 0; m < 4; ++m) {                                                   \
        int row = wr + m*16 + l15;                                                    \
        af[m] = *(const bf16x8*)((const char*)As + row*128 + (((kk*4+lg)^(row&7))<<4)); \
      }                                                                               \
      _Pragma("unroll")                                                               \
      for (int n = 0; n < 4; ++n) {                                                   \
        int row = wc + n*16 + l15;                                                    \
        bfr[n] = *(const bf16x8*)((const char*)Bs + row*128 + (((kk*4+lg)^(row&7))<<4)); \
      }                                                                               \
      _Pragma("unroll")                                                               \
      for (int m = 0; m < 4; ++m)                                                     \
        _Pragma("unroll")                                                             \
        for (int n = 0; n < 4; ++n)                                                   \
          acc[m][n] = __builtin_amdgcn_mfma_f32_16x16x32_bf16(af[m], bfr[n], acc[m][n], 0,0,0); \
    }                                                                                 \
  }

// ---------- K1: QKV projection GEMM (bf16 x bf16) ----------
__global__ __launch_bounds__(256,3) void gemm_qkv_kernel(
    const unsigned short* __restrict__ xb, const unsigned short* __restrict__ wt,
    unsigned short* __restrict__ Qo, unsigned short* __restrict__ Ko,
    unsigned short* __restrict__ Vto) {
  __shared__ __align__(16) unsigned short As[128*64];
  __shared__ __align__(16) unsigned short Bs[128*64];
  const int z = blockIdx.z;
  const int m0 = blockIdx.y*128, n0 = blockIdx.x*128;
  const int t = threadIdx.x, lane = t & 63, wid = t >> 6;
  const int wr = (wid>>1)*64, wc = (wid&1)*64;
  const int l15 = lane & 15, lg = lane >> 4;
  const unsigned short* Ab = xb + (size_t)m0 * D_;
  const unsigned short* Bb = wt + (size_t)z * D_ * D_ + (size_t)n0 * D_;

  f32x4 acc[4][4];
  #pragma unroll
  for (int m=0;m<4;m++)
    #pragma unroll
    for (int n=0;n<4;n++) acc[m][n] = f32x4{0.f,0.f,0.f,0.f};

  GEMM_K_LOOP(Ab, Bb)

  #pragma unroll
  for (int m=0;m<4;m++) {
    #pragma unroll
    for (int n=0;n<4;n++) {
      #pragma unroll
      for (int r=0;r<4;r++) {
        int gm = m0 + wr + m*16 + lg*4 + r;
        int gn = n0 + wc + n*16 + l15;
        int b = gm >> 11, s = gm & (S_-1);
        int h = gn >> 6,  d = gn & 63;
        unsigned short val = f2bf(acc[m][n][r]);
        if (z==0)      Qo[(((size_t)(b*H_+h))*S_ + s)*HD_ + d] = val;
        else if (z==1) Ko[(((size_t)(b*H_+h))*S_ + s)*HD_ + d] = val;
        else           Vto[(((size_t)(b*H_+h))*HD_ + d)*S_ + s] = val;
      }
    }
  }
}

// ---------- K2: causal flash attention (unchanged from round 3) ----------
__global__ __launch_bounds__(256,2) void attn_kernel(
    const unsigned short* __restrict__ Q, const unsigned short* __restrict__ K,
    const unsigned short* __restrict__ Vt, unsigned short* __restrict__ ctx) {
  __shared__ __align__(16) unsigned short KT[2][64*64];
  __shared__ __align__(16) unsigned short VT[2][64*64];
  __shared__ __align__(16) unsigned short PL[4][16*72];
  const int t = threadIdx.x, lane = t & 63, wid = t >> 6;
  const int bh = blockIdx.x & 31;
  const int qt = 31 - (int)(blockIdx.x >> 5);   // heavy tiles first
  const int b = bh >> 4, h = bh & 15;
  const int q0 = qt * 64, qw0 = q0 + wid * 16;
  const int nchunk = qt + 1;
  const unsigned short* Qp = Q  + (size_t)bh * S_ * HD_;
  const unsigned short* Kp = K  + (size_t)bh * S_ * HD_;
  const unsigned short* Vp = Vt + (size_t)bh * HD_ * S_;
  const int l15 = lane & 15, lg = lane >> 4;
  const int rsub = lane >> 3, slot = lane & 7;
  const int sslot = slot ^ rsub;                // source pre-swizzle (row&7 == rsub)

  bf16x8 qf0 = *(const bf16x8*)(Qp + (size_t)(qw0 + l15)*HD_ + lg*8);
  bf16x8 qf1 = *(const bf16x8*)(Qp + (size_t)(qw0 + l15)*HD_ + 32 + lg*8);

  f32x4 o[4];
  #pragma unroll
  for (int dt=0;dt<4;dt++) o[dt] = f32x4{0.f,0.f,0.f,0.f};
  float m = -INFINITY, lsum = 0.f;
  const float c = 0.18033688011112042f;  // log2(e)/8

  auto stage = [&](int ch, int buf) {
    const int kk0 = ch * 64;
    #pragma unroll
    for (int j=0;j<2;j++) {
      int row = 16*wid + 8*j + rsub;
      gload_lds16(Kp + (size_t)(kk0 + row)*HD_ + sslot*8, &KT[buf][(16*wid + 8*j)*64]);
      gload_lds16(Vp + (size_t)row*S_ + kk0 + sslot*8,    &VT[buf][(16*wid + 8*j)*64]);
    }
  };

  stage(0, 0);
  __syncthreads();

  for (int ch=0; ch<nchunk; ++ch) {
    const int cur = ch & 1;
    const int kk0 = ch * 64;
    if (ch + 1 < nchunk) stage(ch+1, cur^1);

    const unsigned short* Kt = &KT[cur][0];
    const unsigned short* Vv = &VT[cur][0];

    f32x4 st[4];
    #pragma unroll
    for (int kt=0; kt<4; ++kt) {
      int row = kt*16 + l15;
      int sw = (row & 7) << 4;
      bf16x8 kf0 = *(const bf16x8*)((const char*)Kt + row*128 + ((lg*16)      ^ sw));
      bf16x8 kf1 = *(const bf16x8*)((const char*)Kt + row*128 + ((64 + lg*16) ^ sw));
      f32x4 z = f32x4{0.f,0.f,0.f,0.f};
      z = __builtin_amdgcn_mfma_f32_16x16x32_bf16(kf0, qf0, z, 0,0,0);
      z = __builtin_amdgcn_mfma_f32_16x16x32_bf16(kf1, qf1, z, 0,0,0);
      st[kt] = z;
    }

    if (ch == nchunk-1) {
      const int q = qw0 + l15;
      #pragma unroll
      for (int kt=0;kt<4;kt++)
        #pragma unroll
        for (int r=0;r<4;r++)
          if (kk0 + kt*16 + lg*4 + r > q) st[kt][r] = -INFINITY;
    }

    float mx = st[0][0];
    #pragma unroll
    for (int kt=0;kt<4;kt++)
      #pragma unroll
      for (int r=0;r<4;r++) mx = fmaxf(mx, st[kt][r]);
    mx = fmaxf(mx, __shfl_xor(mx, 16));
    mx = fmaxf(mx, __shfl_xor(mx, 32));
    float mn = fmaxf(m, mx);
    float corr = exp2f((m - mn) * c);
    m = mn;
    float rs = 0.f;
    #pragma unroll
    for (int kt=0;kt<4;kt++)
      #pragma unroll
      for (int r=0;r<4;r++) {
        float p = exp2f((st[kt][r] - mn) * c);
        st[kt][r] = p;
        rs += p;
      }
    rs += __shfl_xor(rs, 16);
    rs += __shfl_xor(rs, 32);
    lsum = lsum * corr + rs;

    #pragma unroll
    for (int kt=0;kt<4;kt++) {
      s16x4 pk;
      pk[0]=(short)f2bf(st[kt][0]); pk[1]=(short)f2bf(st[kt][1]);
      pk[2]=(short)f2bf(st[kt][2]); pk[3]=(short)f2bf(st[kt][3]);
      *(s16x4*)&PL[wid][l15*72 + kt*16 + lg*4] = pk;
    }

    float oc[4];
    #pragma unroll
    for (int r=0;r<4;r++) oc[r] = __shfl(corr, lg*4 + r);
    #pragma unroll
    for (int dt=0;dt<4;dt++)
      #pragma unroll
      for (int r=0;r<4;r++) o[dt][r] *= oc[r];

    bf16x8 pf0 = *(const bf16x8*)&PL[wid][l15*72 + lg*8];
    bf16x8 pf1 = *(const bf16x8*)&PL[wid][l15*72 + 32 + lg*8];

    #pragma unroll
    for (int dt=0;dt<4;dt++) {
      int row = dt*16 + l15;
      int sw = (row & 7) << 4;
      bf16x8 vf0 = *(const bf16x8*)((const char*)Vv + row*128 + ((lg*16)      ^ sw));
      bf16x8 vf1 = *(const bf16x8*)((const char*)Vv + row*128 + ((64 + lg*16) ^ sw));
      o[dt] = __builtin_amdgcn_mfma_f32_16x16x32_bf16(pf0, vf0, o[dt], 0,0,0);
      o[dt] = __builtin_amdgcn_mfma_f32_16x16x32_bf16(pf1, vf1, o[dt], 0,0,0);
    }

    __syncthreads();
  }

  float li = 1.f / lsum;
  float lr[4];
  #pragma unroll
  for (int r=0;r<4;r++) lr[r] = __shfl(li, lg*4 + r);
  #pragma unroll
  for (int dt=0;dt<4;dt++)
    #pragma unroll
    for (int r=0;r<4;r++) {
      size_t row = (size_t)(b*S_ + qw0 + lg*4 + r);
      ctx[row*D_ + h*HD_ + dt*16 + l15] = f2bf(o[dt][r] * lr[r]);
    }
}

// ---------- K3: output projection GEMM + bias (bf16 -> fp32 out) ----------
__global__ __launch_bounds__(256,3) void gemm_out_kernel(
    const unsigned short* __restrict__ ctx, const unsigned short* __restrict__ WtO,
    const float* __restrict__ bo, float* __restrict__ out) {
  __shared__ __align__(16) unsigned short As[128*64];
  __shared__ __align__(16) unsigned short Bs[128*64];
  const int m0 = blockIdx.y*128, n0 = blockIdx.x*128;
  const int t = threadIdx.x, lane = t & 63, wid = t >> 6;
  const int wr = (wid>>1)*64, wc = (wid&1)*64;
  const int l15 = lane & 15, lg = lane >> 4;
  const unsigned short* Ab = ctx + (size_t)m0 * D_;
  const unsigned short* Bb = WtO + (size_t)n0 * D_;

  f32x4 acc[4][4];
  #pragma unroll
  for (int m=0;m<4;m++)
    #pragma unroll
    for (int n=0;n<4;n++) acc[m][n] = f32x4{0.f,0.f,0.f,0.f};

  GEMM_K_LOOP(Ab, Bb)

  #pragma unroll
  for (int n=0;n<4;n++) {
    float bias = bo[n0 + wc + n*16 + l15];
    #pragma unroll
    for (int m=0;m<4;m++)
      #pragma unroll
      for (int r=0;r<4;r++) {
        int gm = m0 + wr + m*16 + lg*4 + r;
        int gn = n0 + wc + n*16 + l15;
        out[(size_t)gm*D_ + gn] = acc[m][n][r] + bias;
      }
  }
}

extern "C" void kernel_launch(void* const* d_in, const int* in_sizes, int n_in,
                              void* d_out, int out_size, void* d_ws, size_t ws_size,
                              hipStream_t stream) {
  (void)in_sizes; (void)n_in; (void)out_size; (void)ws_size;
  const float* x  = (const float*)d_in[0];
  const float* Wq = (const float*)d_in[1];
  const float* Wk = (const float*)d_in[2];
  const float* Wv = (const float*)d_in[3];
  const float* Wo = (const float*)d_in[4];
  const float* bo = (const float*)d_in[5];
  float* out = (float*)d_out;

  unsigned short* wt  = (unsigned short*)d_ws;            // 4 * D*D bf16 (transposed weights)
  unsigned short* Qb  = wt  + (size_t)4*D_*D_;            // [B,H,S,HD]
  unsigned short* Kb  = Qb  + (size_t)M_*D_;              // [B,H,S,HD]
  unsigned short* Vtb = Kb  + (size_t)M_*D_;              // [B,H,HD,S]
  unsigned short* ctb = Vtb + (size_t)M_*D_;              // [B,S,D]
  unsigned short* xbb = ctb + (size_t)M_*D_;              // [M,D] bf16 x

  xcvt_kernel<<<dim3(M_*D_/(256*8)), 256, 0, stream>>>(x, xbb);
  wtrans_kernel<<<dim3(32,32,4), dim3(32,8), 0, stream>>>(Wq, Wk, Wv, Wo, wt);
  gemm_qkv_kernel<<<dim3(8,32,3), 256, 0, stream>>>(xbb, wt, Qb, Kb, Vtb);
  attn_kernel<<<dim3(1024), 256, 0, stream>>>(Qb, Kb, Vtb, ctb);
  gemm_out_kernel<<<dim3(8,32), 256, 0, stream>>>(ctb, wt + (size_t)3*D_*D_, bo, out);
}

// Round 5
// 119.757 us; speedup vs baseline: 2.7837x; 1.0149x over previous
//
#include <hip/hip_runtime.h>

#define B_ 2
#define S_ 2048
#define D_ 1024
#define H_ 16
#define HD_ 64
#define M_ (B_*S_)

typedef __attribute__((ext_vector_type(8))) short bf16x8;
typedef __attribute__((ext_vector_type(4))) short s16x4;
typedef __attribute__((ext_vector_type(4))) float f32x4;
typedef __attribute__((ext_vector_type(4))) unsigned int u32x4;

static __device__ __forceinline__ unsigned short f2bf(float f) {
  unsigned int u = __builtin_bit_cast(unsigned int, f);
  u += 0x7FFFu + ((u >> 16) & 1u);   // RNE
  return (unsigned short)(u >> 16);
}

static __device__ __forceinline__ unsigned int cvt_pk_bf16(float a, float b) {
  unsigned int r;
  asm("v_cvt_pk_bf16_f32 %0, %1, %2" : "=v"(r) : "v"(a), "v"(b));
  return r;   // lo = bf16(a), hi = bf16(b)
}

static __device__ __forceinline__ void gload_lds16(const void* g, void* l) {
  __builtin_amdgcn_global_load_lds(
      (const __attribute__((address_space(1))) unsigned int*)g,
      (__attribute__((address_space(3))) unsigned int*)l, 16, 0, 0);
}

// ---------- K0a: x fp32 -> bf16 ----------
__global__ __launch_bounds__(256) void xcvt_kernel(const float* __restrict__ x,
                                                   unsigned short* __restrict__ xb) {
  size_t i = ((size_t)blockIdx.x * 256 + threadIdx.x) * 8;
  float4 a = ((const float4*)(x + i))[0];
  float4 b = ((const float4*)(x + i))[1];
  bf16x8 w;
  w[0]=(short)f2bf(a.x); w[1]=(short)f2bf(a.y); w[2]=(short)f2bf(a.z); w[3]=(short)f2bf(a.w);
  w[4]=(short)f2bf(b.x); w[5]=(short)f2bf(b.y); w[6]=(short)f2bf(b.z); w[7]=(short)f2bf(b.w);
  *(bf16x8*)(xb + i) = w;
}

// ---------- K0b: transpose + convert weights: Wt[z][n][k] = bf16(W_z[k][n]) ----------
__global__ void wtrans_kernel(const float* __restrict__ Wq, const float* __restrict__ Wk,
                              const float* __restrict__ Wv, const float* __restrict__ Wo,
                              unsigned short* __restrict__ wt) {
  __shared__ float tile[32][33];
  const float* W = blockIdx.z==0 ? Wq : blockIdx.z==1 ? Wk : blockIdx.z==2 ? Wv : Wo;
  unsigned short* out = wt + (size_t)blockIdx.z * D_ * D_;
  int n0 = blockIdx.x*32, k0 = blockIdx.y*32;
  int tx = threadIdx.x, ty = threadIdx.y;   // 32 x 8
  #pragma unroll
  for (int i=0;i<4;i++) tile[ty+i*8][tx] = W[(size_t)(k0+ty+i*8)*D_ + n0+tx];
  __syncthreads();
  #pragma unroll
  for (int i=0;i<4;i++) out[(size_t)(n0+ty+i*8)*D_ + (k0+tx)] = f2bf(tile[tx][ty+i*8]);
}

// ---------- shared GEMM tile body (m97 structure, BK=64, XOR-swizzled LDS) ----------
#define GEMM_K_LOOP(Abase, Bbase)                                                     \
  for (int ks = 0; ks < 16; ++ks) {                                                   \
    const int k0 = ks * 64;                                                           \
    __syncthreads();                                                                  \
    _Pragma("unroll")                                                                 \
    for (int p = 0; p < 4; ++p) {                                                     \
      int c = p*256 + t;                                                              \
      int row = c >> 3, sl = (c & 7) ^ (row & 7);                                     \
      gload_lds16(Abase + (size_t)row*D_ + k0 + sl*8, &As[(p*256 + wid*64)*8]);       \
    }                                                                                 \
    _Pragma("unroll")                                                                 \
    for (int p = 0; p < 4; ++p) {                                                     \
      int c = p*256 + t;                                                              \
      int row = c >> 3, sl = (c & 7) ^ (row & 7);                                     \
      gload_lds16(Bbase + (size_t)row*D_ + k0 + sl*8, &Bs[(p*256 + wid*64)*8]);       \
    }                                                                                 \
    __syncthreads();                                                                  \
    _Pragma("unroll")                                                                 \
    for (int kk = 0; kk < 2; ++kk) {                                                  \
      bf16x8 af[4], bfr[4];                                                           \
      _Pragma("unroll")                                                               \
      for (int m = 0; m < 4; ++m) {                                                   \
        int row = wr + m*16 + l15;                                                    \
        af[m] = *(const bf16x8*)((const char*)As + row*128 + (((kk*4+lg)^(row&7))<<4)); \
      }                                                                               \
      _Pragma("unroll")                                                               \
      for (int n = 0; n < 4; ++n) {                                                   \
        int row = wc + n*16 + l15;                                                    \
        bfr[n] = *(const bf16x8*)((const char*)Bs + row*128 + (((kk*4+lg)^(row&7))<<4)); \
      }                                                                               \
      _Pragma("unroll")                                                               \
      for (int m = 0; m < 4; ++m)                                                     \
        _Pragma("unroll")                                                             \
        for (int n = 0; n < 4; ++n)                                                   \
          acc[m][n] = __builtin_amdgcn_mfma_f32_16x16x32_bf16(af[m], bfr[n], acc[m][n], 0,0,0); \
    }                                                                                 \
  }

// ---------- K1: QKV projection GEMM (bf16 x bf16) ----------
__global__ __launch_bounds__(256,3) void gemm_qkv_kernel(
    const unsigned short* __restrict__ xb, const unsigned short* __restrict__ wt,
    unsigned short* __restrict__ Qo, unsigned short* __restrict__ Ko,
    unsigned short* __restrict__ Vto) {
  __shared__ __align__(16) unsigned short As[128*64];
  __shared__ __align__(16) unsigned short Bs[128*64];
  const int z = blockIdx.z;
  const int m0 = blockIdx.y*128, n0 = blockIdx.x*128;
  const int t = threadIdx.x, lane = t & 63, wid = t >> 6;
  const int wr = (wid>>1)*64, wc = (wid&1)*64;
  const int l15 = lane & 15, lg = lane >> 4;
  const unsigned short* Ab = xb + (size_t)m0 * D_;
  const unsigned short* Bb = wt + (size_t)z * D_ * D_ + (size_t)n0 * D_;

  f32x4 acc[4][4];
  #pragma unroll
  for (int m=0;m<4;m++)
    #pragma unroll
    for (int n=0;n<4;n++) acc[m][n] = f32x4{0.f,0.f,0.f,0.f};

  GEMM_K_LOOP(Ab, Bb)

  #pragma unroll
  for (int m=0;m<4;m++) {
    #pragma unroll
    for (int n=0;n<4;n++) {
      #pragma unroll
      for (int r=0;r<4;r++) {
        int gm = m0 + wr + m*16 + lg*4 + r;
        int gn = n0 + wc + n*16 + l15;
        int b = gm >> 11, s = gm & (S_-1);
        int h = gn >> 6,  d = gn & 63;
        unsigned short val = f2bf(acc[m][n][r]);
        if (z==0)      Qo[(((size_t)(b*H_+h))*S_ + s)*HD_ + d] = val;
        else if (z==1) Ko[(((size_t)(b*H_+h))*S_ + s)*HD_ + d] = val;
        else           Vto[(((size_t)(b*H_+h))*HD_ + d)*S_ + s] = val;
      }
    }
  }
}

// ---------- K2: causal flash attention v3 (cvt_pk pack, defer-max, 3 blocks/CU) ----------
__global__ __launch_bounds__(256,3) void attn_kernel(
    const unsigned short* __restrict__ Q, const unsigned short* __restrict__ K,
    const unsigned short* __restrict__ Vt, unsigned short* __restrict__ ctx) {
  __shared__ __align__(16) unsigned short KT[2][64*64];
  __shared__ __align__(16) unsigned short VT[2][64*64];
  __shared__ __align__(16) unsigned short PL[4][16*72];
  const int t = threadIdx.x, lane = t & 63, wid = t >> 6;
  const int bh = blockIdx.x & 31;
  const int qt = 31 - (int)(blockIdx.x >> 5);   // heavy tiles first
  const int b = bh >> 4, h = bh & 15;
  const int q0 = qt * 64, qw0 = q0 + wid * 16;
  const int nchunk = qt + 1;
  const unsigned short* Qp = Q  + (size_t)bh * S_ * HD_;
  const unsigned short* Kp = K  + (size_t)bh * S_ * HD_;
  const unsigned short* Vp = Vt + (size_t)bh * HD_ * S_;
  const int l15 = lane & 15, lg = lane >> 4;
  const int rsub = lane >> 3, slot = lane & 7;
  const int sslot = slot ^ rsub;                // source pre-swizzle (row&7 == rsub)

  bf16x8 qf0 = *(const bf16x8*)(Qp + (size_t)(qw0 + l15)*HD_ + lg*8);
  bf16x8 qf1 = *(const bf16x8*)(Qp + (size_t)(qw0 + l15)*HD_ + 32 + lg*8);

  f32x4 o[4];
  #pragma unroll
  for (int dt=0;dt<4;dt++) o[dt] = f32x4{0.f,0.f,0.f,0.f};
  float m = -INFINITY, lsum = 0.f;
  const float c = 0.18033688011112042f;   // log2(e)/8
  const float THRS = 44.36141955583649f;  // 8 / c  (defer-max threshold, exp2-arg units)

  auto stage = [&](int ch, int buf) {
    const int kk0 = ch * 64;
    #pragma unroll
    for (int j=0;j<2;j++) {
      int row = 16*wid + 8*j + rsub;
      gload_lds16(Kp + (size_t)(kk0 + row)*HD_ + sslot*8, &KT[buf][(16*wid + 8*j)*64]);
      gload_lds16(Vp + (size_t)row*S_ + kk0 + sslot*8,    &VT[buf][(16*wid + 8*j)*64]);
    }
  };

  stage(0, 0);
  __syncthreads();

  for (int ch=0; ch<nchunk; ++ch) {
    const int cur = ch & 1;
    const int kk0 = ch * 64;
    if (ch + 1 < nchunk) stage(ch+1, cur^1);

    const unsigned short* Kt = &KT[cur][0];
    const unsigned short* Vv = &VT[cur][0];

    // QK^T swapped: st[kt] holds S^T: k = kk0+kt*16+lg*4+r, q = qw0+l15
    f32x4 st[4];
    #pragma unroll
    for (int kt=0; kt<4; ++kt) {
      int row = kt*16 + l15;
      int sw = (row & 7) << 4;
      bf16x8 kf0 = *(const bf16x8*)((const char*)Kt + row*128 + ((lg*16)      ^ sw));
      bf16x8 kf1 = *(const bf16x8*)((const char*)Kt + row*128 + ((64 + lg*16) ^ sw));
      f32x4 z = f32x4{0.f,0.f,0.f,0.f};
      z = __builtin_amdgcn_mfma_f32_16x16x32_bf16(kf0, qf0, z, 0,0,0);
      z = __builtin_amdgcn_mfma_f32_16x16x32_bf16(kf1, qf1, z, 0,0,0);
      st[kt] = z;
    }

    if (ch == nchunk-1) {  // causal mask (only last chunk crosses the diagonal)
      const int q = qw0 + l15;
      #pragma unroll
      for (int kt=0;kt<4;kt++)
        #pragma unroll
        for (int r=0;r<4;r++)
          if (kk0 + kt*16 + lg*4 + r > q) st[kt][r] = -INFINITY;
    }

    // row max (row q = qw0+l15; spread over 4 lanes lg)
    float mx = st[0][0];
    #pragma unroll
    for (int kt=0;kt<4;kt++)
      #pragma unroll
      for (int r=0;r<4;r++) mx = fmaxf(mx, st[kt][r]);
    mx = fmaxf(mx, __shfl_xor(mx, 16));
    mx = fmaxf(mx, __shfl_xor(mx, 32));

    // defer-max: rescale only when the running max grows past the threshold
    if (__any(mx > m + THRS)) {
      float mn = fmaxf(m, mx);
      float corr = exp2f((m - mn) * c);
      m = mn;
      lsum *= corr;
      float oc[4];
      #pragma unroll
      for (int r=0;r<4;r++) oc[r] = __shfl(corr, lg*4 + r);
      #pragma unroll
      for (int dt=0;dt<4;dt++)
        #pragma unroll
        for (int r=0;r<4;r++) o[dt][r] *= oc[r];
    }

    // P = exp2((S - m)*c), row sum, pack to bf16 via v_cvt_pk
    float rs = 0.f;
    #pragma unroll
    for (int kt=0;kt<4;kt++) {
      #pragma unroll
      for (int r=0;r<4;r++) {
        float p = exp2f((st[kt][r] - m) * c);
        st[kt][r] = p;
        rs += p;
      }
      uint2 pk;
      pk.x = cvt_pk_bf16(st[kt][0], st[kt][1]);
      pk.y = cvt_pk_bf16(st[kt][2], st[kt][3]);
      *(uint2*)&PL[wid][l15*72 + kt*16 + lg*4] = pk;
    }
    rs += __shfl_xor(rs, 16);
    rs += __shfl_xor(rs, 32);
    lsum += rs;

    bf16x8 pf0 = *(const bf16x8*)&PL[wid][l15*72 + lg*8];
    bf16x8 pf1 = *(const bf16x8*)&PL[wid][l15*72 + 32 + lg*8];

    #pragma unroll
    for (int dt=0;dt<4;dt++) {
      int row = dt*16 + l15;
      int sw = (row & 7) << 4;
      bf16x8 vf0 = *(const bf16x8*)((const char*)Vv + row*128 + ((lg*16)      ^ sw));
      bf16x8 vf1 = *(const bf16x8*)((const char*)Vv + row*128 + ((64 + lg*16) ^ sw));
      o[dt] = __builtin_amdgcn_mfma_f32_16x16x32_bf16(pf0, vf0, o[dt], 0,0,0);
      o[dt] = __builtin_amdgcn_mfma_f32_16x16x32_bf16(pf1, vf1, o[dt], 0,0,0);
    }

    __syncthreads();   // drains vmcnt (next chunk staged) + protects K/V + PL buffers
  }

  float li = 1.f / lsum;
  float lr[4];
  #pragma unroll
  for (int r=0;r<4;r++) lr[r] = __shfl(li, lg*4 + r);
  #pragma unroll
  for (int dt=0;dt<4;dt++)
    #pragma unroll
    for (int r=0;r<4;r++) {
      size_t row = (size_t)(b*S_ + qw0 + lg*4 + r);
      ctx[row*D_ + h*HD_ + dt*16 + l15] = f2bf(o[dt][r] * lr[r]);
    }
}

// ---------- K3: output projection GEMM + bias (bf16 -> fp32 out) ----------
__global__ __launch_bounds__(256,3) void gemm_out_kernel(
    const unsigned short* __restrict__ ctx, const unsigned short* __restrict__ WtO,
    const float* __restrict__ bo, float* __restrict__ out) {
  __shared__ __align__(16) unsigned short As[128*64];
  __shared__ __align__(16) unsigned short Bs[128*64];
  const int m0 = blockIdx.y*128, n0 = blockIdx.x*128;
  const int t = threadIdx.x, lane = t & 63, wid = t >> 6;
  const int wr = (wid>>1)*64, wc = (wid&1)*64;
  const int l15 = lane & 15, lg = lane >> 4;
  const unsigned short* Ab = ctx + (size_t)m0 * D_;
  const unsigned short* Bb = WtO + (size_t)n0 * D_;

  f32x4 acc[4][4];
  #pragma unroll
  for (int m=0;m<4;m++)
    #pragma unroll
    for (int n=0;n<4;n++) acc[m][n] = f32x4{0.f,0.f,0.f,0.f};

  GEMM_K_LOOP(Ab, Bb)

  #pragma unroll
  for (int n=0;n<4;n++) {
    float bias = bo[n0 + wc + n*16 + l15];
    #pragma unroll
    for (int m=0;m<4;m++)
      #pragma unroll
      for (int r=0;r<4;r++) {
        int gm = m0 + wr + m*16 + lg*4 + r;
        int gn = n0 + wc + n*16 + l15;
        out[(size_t)gm*D_ + gn] = acc[m][n][r] + bias;
      }
  }
}

extern "C" void kernel_launch(void* const* d_in, const int* in_sizes, int n_in,
                              void* d_out, int out_size, void* d_ws, size_t ws_size,
                              hipStream_t stream) {
  (void)in_sizes; (void)n_in; (void)out_size; (void)ws_size;
  const float* x  = (const float*)d_in[0];
  const float* Wq = (const float*)d_in[1];
  const float* Wk = (const float*)d_in[2];
  const float* Wv = (const float*)d_in[3];
  const float* Wo = (const float*)d_in[4];
  const float* bo = (const float*)d_in[5];
  float* out = (float*)d_out;

  unsigned short* wt  = (unsigned short*)d_ws;            // 4 * D*D bf16 (transposed weights)
  unsigned short* Qb  = wt  + (size_t)4*D_*D_;            // [B,H,S,HD]
  unsigned short* Kb  = Qb  + (size_t)M_*D_;              // [B,H,S,HD]
  unsigned short* Vtb = Kb  + (size_t)M_*D_;              // [B,H,HD,S]
  unsigned short* ctb = Vtb + (size_t)M_*D_;              // [B,S,D]
  unsigned short* xbb = ctb + (size_t)M_*D_;              // [M,D] bf16 x

  xcvt_kernel<<<dim3(M_*D_/(256*8)), 256, 0, stream>>>(x, xbb);
  wtrans_kernel<<<dim3(32,32,4), dim3(32,8), 0, stream>>>(Wq, Wk, Wv, Wo, wt);
  gemm_qkv_kernel<<<dim3(8,32,3), 256, 0, stream>>>(xbb, wt, Qb, Kb, Vtb);
  attn_kernel<<<dim3(1024), 256, 0, stream>>>(Qb, Kb, Vtb, ctb);
  gemm_out_kernel<<<dim3(8,32), 256, 0, stream>>>(ctb, wt + (size_t)3*D_*D_, bo, out);
}